// Round 1
// baseline (1170.355 us; speedup 1.0000x reference)
//
#include <hip/hip_runtime.h>

typedef __attribute__((ext_vector_type(8))) _Float16 half8;
typedef __attribute__((ext_vector_type(4))) float floatx4;

// features: [16, 512, 64, 64] fp32 -> feat[(b<<21) + (c<<12) + n], n = h*64+w
// memory:   [2048, 512] fp32
// out:      [16, 512, 64, 64] fp32 (same layout as features)
// Row r = b*4096 + n. tokens[r][c] = feat[(b<<21)+(c<<12)+n].

__global__ __launch_bounds__(256) void prep_kernel(const float* __restrict__ mem,
                                                   _Float16* __restrict__ mem16,
                                                   _Float16* __restrict__ memtr) {
    int tid = blockIdx.x * 256 + threadIdx.x;   // 0 .. 2048*512-1
    int m = tid >> 9;
    int c = tid & 511;
    _Float16 h = (_Float16)mem[tid];
    mem16[tid] = h;              // [m][c] f16
    memtr[c * 2048 + m] = h;     // [c][m] f16
}

__global__ __launch_bounds__(512, 2) void attn_kernel(const float* __restrict__ feat,
                                                      const _Float16* __restrict__ mem16,
                                                      const _Float16* __restrict__ memtr,
                                                      float* __restrict__ out) {
    // LDS (total ~59 KB)
    __shared__ __align__(16) _Float16 Kt[32 * 264];   // K tile [m_local][c-half 256 (+8 pad)]
    __shared__ __align__(16) _Float16 Kv[512 * 36];   // V^T tile [c][m_local 32 (+4 pad)]
    __shared__ __align__(16) _Float16 Pb[64 * 40];    // P [row][m_local 32 (+8 pad)]
    __shared__ float tmaxb[2][64];
    __shared__ float tsumb[2][64];
    __shared__ float mst[64];
    __shared__ float lst[64];

    const int tid = (int)threadIdx.x;
    const int w   = tid >> 6;     // wave 0..7
    const int L   = tid & 63;
    const int q   = L >> 4;       // quad 0..3
    const int m16 = L & 15;
    const int rt  = w >> 1;       // row-tile 0..3 (16 rows each)
    const int sub = w & 1;        // S: m-half of tile; PV+epilogue: c-half (256)

    const int r0 = (int)blockIdx.x * 64;
    const int b  = r0 >> 12;
    const int nb = r0 & 4095;

    if (tid < 64) { mst[tid] = -1e30f; lst[tid] = 0.0f; }

    // ---- Q A-fragments in registers: rows rt*16+m16, k-chunk q*8 within 32-wide j blocks
    half8 qf[16];
    {
        const float* fb = feat + ((size_t)b << 21) + (size_t)(nb + rt * 16 + m16);
        #pragma unroll
        for (int j = 0; j < 16; ++j) {
            #pragma unroll
            for (int jj = 0; jj < 8; ++jj) {
                qf[j][jj] = (_Float16)fb[(size_t)(j * 32 + q * 8 + jj) << 12];
            }
        }
    }

    floatx4 acc[16];
    #pragma unroll
    for (int f = 0; f < 16; ++f) acc[f] = (floatx4){0.f, 0.f, 0.f, 0.f};

    __syncthreads();

    for (int it = 0; it < 64; ++it) {
        const int m0 = it * 32;

        // ---- stage Kv (full 512x32) + Kt c-half 0 ----
        #pragma unroll
        for (int p = 0; p < 8; ++p) {
            int id = tid + p * 512;
            int c = id >> 3, mm = (id & 7) * 4;
            *(unsigned long long*)&Kv[c * 36 + mm] =
                *(const unsigned long long*)&memtr[(size_t)c * 2048 + m0 + mm];
        }
        #pragma unroll
        for (int p = 0; p < 2; ++p) {
            int id = tid + p * 512;
            int mr = id >> 5, cc = (id & 31) * 8;
            *(int4*)&Kt[mr * 264 + cc] =
                *(const int4*)&mem16[(size_t)(m0 + mr) * 512 + cc];
        }
        __syncthreads();

        // ---- S = Q.K^T, first c-half; wave (rt,sub): S tile rows rt*16, cols sub*16 ----
        floatx4 s = (floatx4){0.f, 0.f, 0.f, 0.f};
        #pragma unroll
        for (int j = 0; j < 8; ++j) {
            half8 bf = *(const half8*)&Kt[(sub * 16 + m16) * 264 + j * 32 + q * 8];
            s = __builtin_amdgcn_mfma_f32_16x16x32_f16(qf[j], bf, s, 0, 0, 0);
        }
        __syncthreads();

        // ---- stage Kt c-half 1 ----
        #pragma unroll
        for (int p = 0; p < 2; ++p) {
            int id = tid + p * 512;
            int mr = id >> 5, cc = (id & 31) * 8;
            *(int4*)&Kt[mr * 264 + cc] =
                *(const int4*)&mem16[(size_t)(m0 + mr) * 512 + 256 + cc];
        }
        __syncthreads();

        // ---- S second c-half + per-tile row max (rows = q*4+i within wave) ----
        #pragma unroll
        for (int j = 0; j < 8; ++j) {
            half8 bf = *(const half8*)&Kt[(sub * 16 + m16) * 264 + j * 32 + q * 8];
            s = __builtin_amdgcn_mfma_f32_16x16x32_f16(qf[8 + j], bf, s, 0, 0, 0);
        }
        float tm[4] = {s[0], s[1], s[2], s[3]};
        #pragma unroll
        for (int msk = 1; msk < 16; msk <<= 1) {
            #pragma unroll
            for (int i = 0; i < 4; ++i) tm[i] = fmaxf(tm[i], __shfl_xor(tm[i], msk));
        }
        if (m16 == 0) {
            #pragma unroll
            for (int i = 0; i < 4; ++i) tmaxb[sub][rt * 16 + q * 4 + i] = tm[i];
        }
        __syncthreads();

        // ---- online-softmax update + P ----
        float al[4], mn[4], ts[4];
        #pragma unroll
        for (int i = 0; i < 4; ++i) {
            int row = rt * 16 + q * 4 + i;
            float t  = fmaxf(tmaxb[0][row], tmaxb[1][row]);
            float mo = mst[row];
            mn[i] = fmaxf(mo, t);
            al[i] = __expf(mo - mn[i]);
            float pv = __expf(s[i] - mn[i]);
            ts[i] = pv;
            Pb[row * 40 + sub * 16 + m16] = (_Float16)pv;
        }
        #pragma unroll
        for (int msk = 1; msk < 16; msk <<= 1) {
            #pragma unroll
            for (int i = 0; i < 4; ++i) ts[i] += __shfl_xor(ts[i], msk);
        }
        if (m16 == 0) {
            #pragma unroll
            for (int i = 0; i < 4; ++i) tsumb[sub][rt * 16 + q * 4 + i] = ts[i];
        }
        __syncthreads();

        // ---- state update (one writer per row) ----
        if (sub == 0 && m16 == 0) {
            #pragma unroll
            for (int i = 0; i < 4; ++i) {
                int row = rt * 16 + q * 4 + i;
                lst[row] = lst[row] * al[i] + tsumb[0][row] + tsumb[1][row];
                mst[row] = mn[i];
            }
        }
        // ---- rescale O accumulator (skip when no max changed) ----
        bool need = (al[0] < 1.f) || (al[1] < 1.f) || (al[2] < 1.f) || (al[3] < 1.f);
        if (__ballot(need)) {
            #pragma unroll
            for (int f = 0; f < 16; ++f) {
                acc[f][0] *= al[0]; acc[f][1] *= al[1];
                acc[f][2] *= al[2]; acc[f][3] *= al[3];
            }
        }
        // ---- O += P.V ; wave (rt,sub): rows rt*16, c-half sub*256 ----
        half8 pf = *(const half8*)&Pb[(rt * 16 + m16) * 40 + q * 8];
        #pragma unroll
        for (int f = 0; f < 16; ++f) {
            half8 vf = *(const half8*)&Kv[(sub * 256 + f * 16 + m16) * 36 + q * 8];
            acc[f] = __builtin_amdgcn_mfma_f32_16x16x32_f16(pf, vf, acc[f], 0, 0, 0);
        }
        __syncthreads();
    }

    // ---- epilogue: divide by l, transpose 16x16 tiles through per-wave LDS slab,
    //      store coalesced along n ----
    float inv[4];
    #pragma unroll
    for (int i = 0; i < 4; ++i) inv[i] = 1.0f / lst[rt * 16 + q * 4 + i];

    float* slab = ((float*)Kt) + w * 288;          // 272 used, disjoint per wave
    const size_t obase = ((size_t)b << 21) + (size_t)(nb + rt * 16);
    #pragma unroll
    for (int f = 0; f < 16; ++f) {
        int c0 = sub * 256 + f * 16;
        #pragma unroll
        for (int i = 0; i < 4; ++i)
            slab[m16 * 17 + q * 4 + i] = acc[f][i] * inv[i];   // [c_local][n_local]
        #pragma unroll
        for (int g = 0; g < 4; ++g) {
            int cl = g * 4 + q;
            out[obase + ((size_t)(c0 + cl) << 12) + m16] = slab[cl * 17 + m16];
        }
    }
}

extern "C" void kernel_launch(void* const* d_in, const int* in_sizes, int n_in,
                              void* d_out, int out_size, void* d_ws, size_t ws_size,
                              hipStream_t stream) {
    (void)in_sizes; (void)n_in; (void)out_size; (void)ws_size;
    const float* feat = (const float*)d_in[0];
    const float* mem  = (const float*)d_in[1];
    float* outp = (float*)d_out;
    _Float16* mem16 = (_Float16*)d_ws;                       // 2 MB
    _Float16* memtr = mem16 + (size_t)2048 * 512;            // 2 MB
    hipLaunchKernelGGL(prep_kernel, dim3((2048 * 512) / 256), dim3(256), 0, stream,
                       mem, mem16, memtr);
    hipLaunchKernelGGL(attn_kernel, dim3(1024), dim3(512), 0, stream,
                       feat, mem16, memtr, outp);
}

// Round 2
// 1152.023 us; speedup vs baseline: 1.0159x; 1.0159x over previous
//
#include <hip/hip_runtime.h>

typedef __attribute__((ext_vector_type(8))) _Float16 half8;
typedef __attribute__((ext_vector_type(16))) float floatx16;

// features: [16, 512, 64, 64] fp32 -> feat[(b<<21) + (c<<12) + n], n = h*64+w
// memory:   [2048, 512] fp32 (K == V)
// out:      [16, 512, 64, 64] fp32
//
// Ktile (ws): A-frag layout for S^T=K*Q^T:  Ktile[(t*32+ks)*512 + L*8 + j]
//   = K[t*32 + (L&31)][ks*16 + (L>>5)*8 + j],  t=0..63 m-tiles, ks=0..31 c-chunks
// Vtile (ws): A-frag layout for O^T=V^T*P:   Vtile[((t*2+kv)*16+ct)*512 + L*8 + j]
//   = V[t*32 + kv*16 + (L>>5)*8 + j][ct*32 + (L&31)]

__global__ __launch_bounds__(256) void prep_kernel(const float* __restrict__ mem,
                                                   _Float16* __restrict__ Ktile,
                                                   _Float16* __restrict__ Vtile) {
    __shared__ _Float16 T[32 * 520];   // tile [m_local][c], stride 520
    const int t = blockIdx.x;          // m-tile 0..63
    const int tid = threadIdx.x;

    #pragma unroll
    for (int rep = 0; rep < 16; ++rep) {
        int idx = rep * 1024 + tid * 4;            // 0..16383
        float4 v = *(const float4*)&mem[(size_t)t * 16384 + idx];
        int row = idx >> 9, col = idx & 511;
        T[row * 520 + col + 0] = (_Float16)v.x;
        T[row * 520 + col + 1] = (_Float16)v.y;
        T[row * 520 + col + 2] = (_Float16)v.z;
        T[row * 520 + col + 3] = (_Float16)v.w;
    }
    __syncthreads();

    // Ktile: 32 ks * 64 lanes = 2048 groups of 8
    #pragma unroll
    for (int rep = 0; rep < 8; ++rep) {
        int u = rep * 256 + tid;
        int ks = u >> 6, L = u & 63;
        half8 kv = *(const half8*)&T[(L & 31) * 520 + ks * 16 + (L >> 5) * 8];
        *(half8*)&Ktile[(size_t)((t * 32 + ks) * 512 + L * 8)] = kv;
    }
    // Vtile: 2 kv * 16 ct * 64 lanes = 2048 groups of 8 (transposed reads)
    #pragma unroll
    for (int rep = 0; rep < 8; ++rep) {
        int u = rep * 256 + tid;
        int kv = u >> 10, ct = (u >> 6) & 15, L = u & 63;
        int c = ct * 32 + (L & 31);
        int mloc = kv * 16 + (L >> 5) * 8;
        half8 vv;
        #pragma unroll
        for (int j = 0; j < 8; ++j) vv[j] = T[(mloc + j) * 520 + c];
        *(half8*)&Vtile[(size_t)(((t * 2 + kv) * 16 + ct) * 512 + L * 8)] = vv;
    }
}

__global__ __launch_bounds__(256, 2) void attn_kernel(const float* __restrict__ feat,
                                                      const _Float16* __restrict__ Ktile,
                                                      const _Float16* __restrict__ Vtile,
                                                      float* __restrict__ out) {
    // small exchange LDS (~13.3 KB)
    __shared__ float Xc[4][8][64];        // partial-S exchange
    __shared__ unsigned int Px[4][4][64]; // P B-frag exchange (packed f16)
    __shared__ float Tm[4][32];           // per-tile row max
    __shared__ float Ts[4][32];           // per-tile row sum

    const int tid = (int)threadIdx.x;
    const int w  = tid >> 6;        // wave 0..3
    const int L  = tid & 63;
    const int r  = L & 31;          // query col within row-group
    const int h  = L >> 5;          // lane half
    const int p  = w & 1;           // k-split / c-split
    const int rg = w >> 1;          // row-group 0..1
    const int w2 = w & ~1;          // pair base

    const int r0 = (int)blockIdx.x * 64;
    const int b  = r0 >> 12;
    const int nb = r0 & 4095;

    // ---- Q B-fragments: 32 rows (rg), c-half (p): qb[ks][j] = Q[r][p*256+ks*16+h*8+j]
    half8 qb[16];
    {
        const float* qp = feat + ((size_t)b << 21) + (size_t)(nb + rg * 32 + r);
        #pragma unroll
        for (int ks = 0; ks < 16; ++ks) {
            #pragma unroll
            for (int j = 0; j < 8; ++j) {
                qb[ks][j] = (_Float16)qp[(size_t)(p * 256 + ks * 16 + h * 8 + j) << 12];
            }
        }
    }

    floatx16 acc[8];
    #pragma unroll
    for (int i = 0; i < 8; ++i) acc[i] = (floatx16)0.0f;

    float mo = -1e30f, l = 0.0f;

    for (int t = 0; t < 64; ++t) {
        // ---- S^T partial over my c-half (16 k-steps, 2 chains) ----
        floatx16 s0 = (floatx16)0.0f, s1 = (floatx16)0.0f;
        const _Float16* kt = Ktile + ((size_t)((t * 32 + p * 16) * 512) + L * 8);
        #pragma unroll
        for (int ksl = 0; ksl < 16; ksl += 2) {
            half8 a0 = *(const half8*)(kt + (size_t)ksl * 512);
            half8 a1 = *(const half8*)(kt + (size_t)(ksl + 1) * 512);
            s0 = __builtin_amdgcn_mfma_f32_32x32x16_f16(a0, qb[ksl], s0, 0, 0, 0);
            s1 = __builtin_amdgcn_mfma_f32_32x32x16_f16(a1, qb[ksl + 1], s1, 0, 0, 0);
        }
        float sp[16];
        #pragma unroll
        for (int k = 0; k < 16; ++k) sp[k] = s0[k] + s1[k];

        // write the half my partner owns (partner base = (1-p)*8)
        const int ob = (1 - p) * 8;
        #pragma unroll
        for (int k = 0; k < 8; ++k) Xc[w][k][L] = sp[ob + k];
        __syncthreads();   // B1

        // combine: I own regs p*8..p*8+7  (m = p*16 + (k&3)+8*(k>>2)+4h)
        float so[8];
        {
            const int myb = p * 8;
            #pragma unroll
            for (int k = 0; k < 8; ++k) so[k] = sp[myb + k] + Xc[w ^ 1][k][L];
        }

        // tile row-max (per lane = per query r), combine lane halves
        float tm = so[0];
        #pragma unroll
        for (int k = 1; k < 8; ++k) tm = fmaxf(tm, so[k]);
        tm = fmaxf(tm, __shfl_xor(tm, 32));
        if (L < 32) Tm[w][L] = tm;
        __syncthreads();   // B2

        const float mn = fmaxf(mo, fmaxf(Tm[w2][r], Tm[w2 + 1][r]));
        const float alpha = __expf(mo - mn);
        mo = mn;

        float pv[8], ts = 0.0f;
        #pragma unroll
        for (int k = 0; k < 8; ++k) { pv[k] = __expf(so[k] - mn); ts += pv[k]; }
        ts += __shfl_xor(ts, 32);
        if (L < 32) Ts[w][L] = ts;

        // assemble my P B-frag (covers m-local kv=p): cross lane-half exchange
        float oth[8];
        #pragma unroll
        for (int k = 0; k < 8; ++k) oth[k] = __shfl_xor(pv[k], 32);
        half8 pf;
        #pragma unroll
        for (int jj = 0; jj < 4; ++jj) {
            float lo = (h == 0) ? pv[jj]  : oth[jj + 4];
            float hi = (h == 0) ? oth[jj] : pv[jj + 4];
            pf[jj]     = (_Float16)lo;
            pf[jj + 4] = (_Float16)hi;
        }
        {
            const unsigned int* pfu = (const unsigned int*)&pf;
            #pragma unroll
            for (int d = 0; d < 4; ++d) Px[w][d][L] = pfu[d];
        }
        __syncthreads();   // B3

        l = l * alpha + Ts[w2][r] + Ts[w2 + 1][r];

        half8 pother;
        {
            unsigned int po[4];
            #pragma unroll
            for (int d = 0; d < 4; ++d) po[d] = Px[w ^ 1][d][L];
            pother = *(const half8*)po;
        }
        const half8 pk0 = p == 0 ? pf : pother;   // m-local 0..15
        const half8 pk1 = p == 0 ? pother : pf;   // m-local 16..31

        if (__ballot(alpha < 0.999999f)) {
            #pragma unroll
            for (int i = 0; i < 8; ++i) {
                #pragma unroll
                for (int k = 0; k < 16; ++k) acc[i][k] *= alpha;
            }
        }

        // ---- O^T += V^T * P  (my c-half: ct = p*8 + 0..7) ----
        const _Float16* vt = Vtile + ((size_t)((t * 32 + p * 8) * 512) + L * 8);
        #pragma unroll
        for (int ct = 0; ct < 8; ++ct) {
            half8 v0 = *(const half8*)(vt + (size_t)(ct * 512));
            half8 v1 = *(const half8*)(vt + (size_t)((16 + ct) * 512));
            acc[ct] = __builtin_amdgcn_mfma_f32_32x32x16_f16(v0, pk0, acc[ct], 0, 0, 0);
            acc[ct] = __builtin_amdgcn_mfma_f32_32x32x16_f16(v1, pk1, acc[ct], 0, 0, 0);
        }
    }

    // ---- epilogue: scale by 1/l, direct coalesced stores (col = n = lane) ----
    const float invl = 1.0f / l;
    const size_t ob = ((size_t)b << 21) + (size_t)(nb + rg * 32 + r);
    #pragma unroll
    for (int ct = 0; ct < 8; ++ct) {
        const int cbase = p * 256 + ct * 32 + 4 * h;
        #pragma unroll
        for (int k = 0; k < 16; ++k) {
            int cl = (k & 3) + 8 * (k >> 2);
            out[ob + ((size_t)(cbase + cl) << 12)] = acc[ct][k] * invl;
        }
    }
}

extern "C" void kernel_launch(void* const* d_in, const int* in_sizes, int n_in,
                              void* d_out, int out_size, void* d_ws, size_t ws_size,
                              hipStream_t stream) {
    (void)in_sizes; (void)n_in; (void)out_size; (void)ws_size;
    const float* feat = (const float*)d_in[0];
    const float* mem  = (const float*)d_in[1];
    float* outp = (float*)d_out;
    _Float16* Ktile = (_Float16*)d_ws;                        // 2 MB
    _Float16* Vtile = Ktile + (size_t)2048 * 512;             // 2 MB
    hipLaunchKernelGGL(prep_kernel, dim3(64), dim3(256), 0, stream, mem, Ktile, Vtile);
    hipLaunchKernelGGL(attn_kernel, dim3(1024), dim3(256), 0, stream,
                       feat, Ktile, Vtile, outp);
}